// Round 2
// baseline (665.182 us; speedup 1.0000x reference)
//
#include <hip/hip_runtime.h>

// Light-field disparity cost volume.
// x:   (B=2, C=16, N=25, H=128, W=128) fp32
// out: (B, C, N, D=9, H, W) fp32
// out[b,c,n,di,h,w] = x[b,c,n, h + d*(2 - n/5), w + d*(2 - n%5)], d = di-4,
// zero where shifted indices fall outside [0,128).
//
// Each thread produces 16 consecutive output words (4 float4 stores) for one
// (bc,n,di,h). Source words [16*w16+dc .. +15] are gathered with 5 ALIGNED
// float4 loads + a wave-uniform funnel select (dc depends only on (n,di),
// which is constant across a 64-lane wave). 9 VMEM instrs / 16 floats vs 20
// before -> attacks the VMEM-issue bound.

typedef float f4 __attribute__((ext_vector_type(4)));

constexpr int N_VIEWS = 25;
constexpr int NDISP   = 9;
constexpr int H       = 128;
constexpr int W       = 128;
constexpr int WBLK    = W / 4;   // 32 aligned float4 blocks per row

template<int R>
__device__ __forceinline__ void gather_row(const float* __restrict__ row,
                                           int w16, int q0, f4* __restrict__ op) {
    constexpr int NB = (R == 0) ? 4 : 5;
    float w[20];
    #pragma unroll
    for (int j = 0; j < NB; ++j) {
        int B = (w16 << 2) + q0 + j;                 // aligned block index
        bool v = (unsigned)B < (unsigned)WBLK;
        const f4* p = reinterpret_cast<const f4*>(row) + (v ? B : 0);
        f4 t = *p;
        w[4*j+0] = v ? t[0] : 0.f;
        w[4*j+1] = v ? t[1] : 0.f;
        w[4*j+2] = v ? t[2] : 0.f;
        w[4*j+3] = v ? t[3] : 0.f;
    }
    #pragma unroll
    for (int k = 0; k < 4; ++k) {
        f4 o = { w[R + 4*k + 0], w[R + 4*k + 1], w[R + 4*k + 2], w[R + 4*k + 3] };
        __builtin_nontemporal_store(o, op + k);
    }
}

__global__ __launch_bounds__(256) void build_cost_kernel(
    const float* __restrict__ x, float* __restrict__ out, int total) {
    int idx = blockIdx.x * blockDim.x + threadIdx.x;
    if (idx >= total) return;

    // idx -> (plane=(bc,n), di, hh, w16); w16 fastest (8 per row)
    int w16 = idx & 7;
    int hh  = (idx >> 3) & (H - 1);
    int t   = idx >> 10;
    int di  = t % NDISP;
    int pn  = t / NDISP;           // bc*25 + n
    int n   = pn % N_VIEWS;
    int a1  = n / 5;
    int a2  = n - a1 * 5;
    int d   = di - 4;
    int sh  = hh + d * (2 - a1);   // shifted source row
    int dc  = d * (2 - a2);        // column shift, wave-uniform

    f4* op = reinterpret_cast<f4*>(out) + (size_t)idx * 4;

    if ((unsigned)sh >= (unsigned)H) {
        f4 z = {0.f, 0.f, 0.f, 0.f};
        #pragma unroll
        for (int k = 0; k < 4; ++k) __builtin_nontemporal_store(z, op + k);
        return;
    }

    const float* row = x + ((size_t)(pn * H + sh)) * W;
    int q0 = dc >> 2;              // floor(dc/4), wave-uniform
    int r  = dc & 3;               // wave-uniform -> uniform branch
    switch (r) {
        case 0: gather_row<0>(row, w16, q0, op); break;
        case 1: gather_row<1>(row, w16, q0, op); break;
        case 2: gather_row<2>(row, w16, q0, op); break;
        default: gather_row<3>(row, w16, q0, op); break;
    }
}

extern "C" void kernel_launch(void* const* d_in, const int* in_sizes, int n_in,
                              void* d_out, int out_size, void* d_ws, size_t ws_size,
                              hipStream_t stream) {
    const float* x = (const float*)d_in[0];
    float* out = (float*)d_out;
    int total = out_size / 16;                 // 7,372,800 threads
    int blocks = (total + 255) / 256;          // 28,800 blocks
    build_cost_kernel<<<blocks, 256, 0, stream>>>(x, out, total);
}

// Round 3
// 89.312 us; speedup vs baseline: 7.4478x; 7.4478x over previous
//
#include <hip/hip_runtime.h>

// Light-field disparity cost volume.
// x:   (B=2, C=16, N=25, H=128, W=128) fp32
// out: (B, C, N, D=9, H, W) fp32
// out[b,c,n,di,h,w] = x[b,c,n, h + d*(2 - n/5), w + d*(2 - n%5)], d = di-4,
// zero where shifted indices fall outside [0,128).
//
// Layout: each wave owns 256 consecutive output float4s (one tile, never
// crossing a (plane,di) image since 4096 f4/image % 256 == 0). Lane i handles
// f4s {base+i, base+64+i, base+128+i, base+192+i} -> every store instruction
// is lane-contiguous (64 lanes x 16 B = 1 KiB full lines; nontemporal safe).
// Each output f4 = funnel-select of 2 aligned source f4 loads (1 if dc%4==0);
// dc is wave-uniform so the switch(r) is a uniform branch with compile-time
// shuffles. 3 VMEM per output f4 vs round-1's 5 (VMEM-issue bound).

typedef float f4 __attribute__((ext_vector_type(4)));

constexpr int N_VIEWS = 25;
constexpr int NDISP   = 9;
constexpr int H       = 128;
constexpr int W       = 128;
constexpr int WBLK    = W / 4;        // 32 aligned f4 blocks per row
constexpr int IMG4    = H * WBLK;     // 4096 f4 per (plane) image

template<int R>
__device__ __forceinline__ void do_wave(const f4* __restrict__ plane,
                                        f4* __restrict__ op,
                                        int base, int lane, int dh, int q0) {
    #pragma unroll
    for (int k = 0; k < 4; ++k) {
        int fi = base + (k << 6) + lane;     // global f4 index
        int hh = (fi >> 5) & (H - 1);
        int b4 = fi & (WBLK - 1);
        int sh = hh + dh;
        f4 o = {0.f, 0.f, 0.f, 0.f};
        if ((unsigned)sh < (unsigned)H) {
            const f4* row = plane + sh * WBLK;
            int B0 = b4 + q0;
            bool v0 = (unsigned)B0 < (unsigned)WBLK;
            f4 t0 = row[v0 ? B0 : 0];
            if (!v0) t0 = (f4){0.f, 0.f, 0.f, 0.f};
            if (R == 0) {
                o = t0;
            } else {
                int B1 = B0 + 1;
                bool v1 = (unsigned)B1 < (unsigned)WBLK;
                f4 t1 = row[v1 ? B1 : 0];
                if (!v1) t1 = (f4){0.f, 0.f, 0.f, 0.f};
                float w[8] = {t0[0], t0[1], t0[2], t0[3],
                              t1[0], t1[1], t1[2], t1[3]};
                o = (f4){w[R + 0], w[R + 1], w[R + 2], w[R + 3]};
            }
        }
        __builtin_nontemporal_store(o, op + fi);
    }
}

__global__ __launch_bounds__(256) void build_cost_kernel(
    const float* __restrict__ x, float* __restrict__ out) {
    int wave = (blockIdx.x << 2) + (threadIdx.x >> 6);
    int lane = threadIdx.x & 63;
    int base = wave << 8;                  // first f4 of this wave's tile

    int pid = base >> 12;                  // (bc*25+n)*9 + di  (wave-uniform)
    int di  = pid % NDISP;
    int pn  = pid / NDISP;                 // bc*25 + n
    int n   = pn % N_VIEWS;
    int a1  = n / 5;
    int a2  = n - a1 * 5;
    int d   = di - 4;
    int dh  = d * (2 - a1);                // row shift   (uniform)
    int dc  = d * (2 - a2);                // col shift   (uniform)
    int q0  = dc >> 2;                     // floor(dc/4) (arith shift ok)
    int r   = dc & 3;

    const f4* plane = reinterpret_cast<const f4*>(x) + (size_t)pn * IMG4;
    f4* op = reinterpret_cast<f4*>(out);

    switch (r) {                           // wave-uniform branch
        case 0:  do_wave<0>(plane, op, base, lane, dh, q0); break;
        case 1:  do_wave<1>(plane, op, base, lane, dh, q0); break;
        case 2:  do_wave<2>(plane, op, base, lane, dh, q0); break;
        default: do_wave<3>(plane, op, base, lane, dh, q0); break;
    }
}

extern "C" void kernel_launch(void* const* d_in, const int* in_sizes, int n_in,
                              void* d_out, int out_size, void* d_ws, size_t ws_size,
                              hipStream_t stream) {
    const float* x = (const float*)d_in[0];
    float* out = (float*)d_out;
    int total_f4 = out_size / 4;                 // 29,491,200
    int threads  = total_f4 / 4;                 // 7,372,800 (4 f4/thread)
    int blocks   = threads / 256;                // 28,800
    build_cost_kernel<<<blocks, 256, 0, stream>>>(x, out);
}